// Round 1
// 872.369 us; speedup vs baseline: 1.0115x; 1.0115x over previous
//
#include <hip/hip_runtime.h>
#include <cstdint>
#include <cstddef>

#define DI __device__ __forceinline__

typedef short bf16x8 __attribute__((ext_vector_type(8)));
typedef float f32x4  __attribute__((ext_vector_type(4)));
typedef _Float16 half2v __attribute__((ext_vector_type(2)));

typedef const uint32_t __attribute__((address_space(1)))* gptr_t;
typedef uint32_t       __attribute__((address_space(3)))* lptr_t;

DI void load_lds16(const void* g, void* l_wave_uniform) {
#if __has_builtin(__builtin_amdgcn_global_load_lds)
  __builtin_amdgcn_global_load_lds((gptr_t)g, (lptr_t)l_wave_uniform, 16, 0, 0);
#else
  int lane = threadIdx.x & 63;
  *(uint4*)((char*)l_wave_uniform + lane * 16) = *(const uint4*)g;
#endif
}

DI ushort f2bf(float f) {  // round-to-nearest-even fp32 -> bf16
  uint32_t u = __builtin_bit_cast(uint32_t, f);
  u += 0x7fffu + ((u >> 16) & 1u);
  return (ushort)(u >> 16);
}

DI half2v h2cast(uint32_t u) { return __builtin_bit_cast(half2v, u); }

#if __has_builtin(__builtin_amdgcn_fdot2)
#define FDOT2(a, b, c) __builtin_amdgcn_fdot2((a), (b), (c), false)
#else
DI float fdot2_fb(half2v a, half2v b, float c) {
  return c + (float)a.x * (float)b.x + (float)a.y * (float)b.y;
}
#define FDOT2(a, b, c) fdot2_fb((a), (b), (c))
#endif

// ---------------------------------------------------------------------------
// Weight conversion kernels
// ---------------------------------------------------------------------------

// W1cat[1536][1024] bf16: rows 0..767 = Wih1, rows 768..1535 = Wih2[:,256:1280]
__global__ void cvt_w1cat(const float* __restrict__ W1, const float* __restrict__ W2,
                          ushort* __restrict__ dst) {
  int idx = blockIdx.x * 256 + threadIdx.x;   // 0 .. 393215
  int e = idx * 4;
  int row = e >> 10;
  int col = e & 1023;
  const float* src = (row < 768) ? (W1 + (size_t)row * 1024 + col)
                                 : (W2 + (size_t)(row - 768) * 1280 + 256 + col);
  float4 f = *(const float4*)src;
  ushort4 o; o.x = f2bf(f.x); o.y = f2bf(f.y); o.z = f2bf(f.z); o.w = f2bf(f.w);
  *(ushort4*)(dst + e) = o;
}

// Wd_bf16 padded [10112][256]
__global__ void cvt_wd(const float* __restrict__ Wd, ushort* __restrict__ dst) {
  int idx = blockIdx.x * 256 + threadIdx.x;   // 0 .. 647167
  int e = idx * 4;
  int row = e >> 8;
  int col = e & 255;
  ushort4 o;
  if (row < 10000) {
    float4 f = *(const float4*)(Wd + (size_t)row * 256 + col);
    o.x = f2bf(f.x); o.y = f2bf(f.y); o.z = f2bf(f.z); o.w = f2bf(f.w);
  } else {
    o.x = 0; o.y = 0; o.z = 0; o.w = 0;
  }
  *(ushort4*)(dst + e) = o;
}

// Whh1[768][256] + Whh2[768][256] fp32 -> packed f16 pairs, contiguous
// dst[0..98303] = Whh1 packed, dst[98304..196607] = Whh2 packed (one launch)
__global__ void cvt_whh(const float* __restrict__ W1, const float* __restrict__ W2,
                        uint32_t* __restrict__ dst) {
  int idx = blockIdx.x * 256 + threadIdx.x;   // 0 .. 196607
  const float* W = W1;
  int i = idx;
  if (i >= 98304) { W = W2; i -= 98304; }
  int row = i >> 7;
  int p = i & 127;
  float2 f = *(const float2*)(W + (size_t)row * 256 + p * 2);
  half2v h; h.x = (_Float16)f.x; h.y = (_Float16)f.y;
  dst[idx] = __builtin_bit_cast(uint32_t, h);
}

// emb gather: row r = t*B+b, E[token[r]] fp32 -> bf16 [8192][1024]
__global__ void gather_emb(const int* __restrict__ tok, const float* __restrict__ E,
                           ushort* __restrict__ emb) {
  int row = blockIdx.x;
  int t = threadIdx.x;          // 0..255, 4 elems each
  int v = tok[row];
  float4 f = *((const float4*)(E + (size_t)v * 1024) + t);
  ushort4 o; o.x = f2bf(f.x); o.y = f2bf(f.y); o.z = f2bf(f.z); o.w = f2bf(f.w);
  *((ushort4*)(emb + (size_t)row * 1024) + t) = o;
}

// ---------------------------------------------------------------------------
// GEMM: C[M,Nout] = A[M,K] * B[Npad,K]^T (+bias).  A,B bf16 K-contig, C fp32.
// BM=BN=128, BK=64, 256 threads (4 waves), each wave a 64x64 subtile.
// LDS chunk-XOR swizzle: 16B chunk c of row r lives at physical chunk c^(r&7).
// ---------------------------------------------------------------------------
template <bool BIAS, bool GUARD>
__global__ __launch_bounds__(256) void gemm_bt(
    const ushort* __restrict__ A, const ushort* __restrict__ B,
    float* __restrict__ C, const float* __restrict__ bias, int M, int K, int Nout) {
  __shared__ __align__(16) ushort As[128 * 64];
  __shared__ __align__(16) ushort Bs[128 * 64];
  const int t = threadIdx.x;
  const int wave = t >> 6, lane = t & 63;
  const int m0 = blockIdx.x * 128, n0 = blockIdx.y * 128;
  const int RM = (wave >> 1) * 64, RN = (wave & 1) * 64;
  const int lm = lane & 15, kg = lane >> 4;   // kg in 0..3

  f32x4 acc[4][4] = {};

  for (int k0 = 0; k0 < K; k0 += 64) {
#pragma unroll
    for (int i = 0; i < 4; ++i) {
      int off = i * 4096 + t * 16;       // byte offset within 16KB tile
      int row = off >> 7;                // /128 bytes per row
      int physc = (off >> 4) & 7;        // physical 16B chunk within row
      int gc = physc ^ (row & 7);        // logical (global) chunk
      int ub = i * 4096 + wave * 1024;   // wave-uniform LDS byte base
      const ushort* ga = A + (size_t)(m0 + row) * K + k0 + gc * 8;
      load_lds16(ga, (char*)As + ub);
      const ushort* gb = B + (size_t)(n0 + row) * K + k0 + gc * 8;
      load_lds16(gb, (char*)Bs + ub);
    }
    __syncthreads();
#pragma unroll
    for (int kk = 0; kk < 64; kk += 32) {
      const int lc = (kk >> 3) + kg;     // logical chunk for this fragment
      bf16x8 af[4], bfr[4];
#pragma unroll
      for (int i = 0; i < 4; ++i) {
        int ra = RM + i * 16 + lm;
        int rb = RN + i * 16 + lm;
        af[i]  = *(const bf16x8*)(As + ra * 64 + ((lc ^ (ra & 7)) << 3));
        bfr[i] = *(const bf16x8*)(Bs + rb * 64 + ((lc ^ (rb & 7)) << 3));
      }
#pragma unroll
      for (int i = 0; i < 4; ++i)
#pragma unroll
        for (int j = 0; j < 4; ++j)
          acc[i][j] = __builtin_amdgcn_mfma_f32_16x16x32_bf16(af[i], bfr[j], acc[i][j], 0, 0, 0);
    }
    __syncthreads();
  }

  const int rg = lane >> 4;   // row group 0..3
#pragma unroll
  for (int i = 0; i < 4; ++i) {
    int grow = m0 + RM + i * 16 + rg * 4;
#pragma unroll
    for (int j = 0; j < 4; ++j) {
      int gcol = n0 + RN + j * 16 + lm;
      if (GUARD && gcol >= Nout) continue;
      float bv = BIAS ? bias[gcol] : 0.f;
#pragma unroll
      for (int r = 0; r < 4; ++r)
        C[(size_t)(grow + r) * Nout + gcol] = acc[i][j][r] + bv;
    }
  }
}

// ---------------------------------------------------------------------------
// GRU scan v2: one 512-thread block per batch element.
// Lane pair (t, t^1) splits K=256 in half; EACH thread computes the partial
// dot of ALL THREE gate rows (r=j, z=256+j, n=512+j) for its h-index j=t>>1
// over its K-half.  Recurrent weights register-resident: 3 x 16 uint4 = 192
// VGPRs (fits 2 waves/SIMD, launch_bounds(512,2) -> 256-VGPR cap).
//
// vs previous 768-thread version:
//   - DS instrs/step: 384 -> 128 ds_read_b128 (16/wave x 8 waves, 2-way
//     broadcast per instr = free per m136)           [DS-issue bound fix]
//   - barriers/step: 2 -> 1 (double-buffered hpk: read buf[t&1], write
//     buf[(t+1)&1]; one barrier separates step-t reads from step-t+1 writes)
//   - no rz[] LDS round-trip: r,z,n live on the same lane pair, combined
//     with __shfl_xor butterflies.
// Same VALU work (768 cy/SIMD/step floor), same 64 blocks.
// ---------------------------------------------------------------------------
__global__ __launch_bounds__(512, 2) void gru_scan(
    const uint32_t* __restrict__ Wpk,      // [768][128] f16-pairs of Whh
    const float* __restrict__ xg_all,      // [8192][1536] fp32 input gates
    int xg_off,
    const float* __restrict__ bih, const float* __restrict__ bhh,
    const float* __restrict__ Wih2,        // gru2 only: [768][1280] fp32 (else null)
    const float* __restrict__ h1in,        // gru2 only: [64][256] fp32
    float* __restrict__ hfin_ws,           // gru1: h1 scratch (else null)
    float* __restrict__ hfin_out,          // gru1: d_out h1 region (else null)
    ushort* __restrict__ preds)            // gru2: bf16 [8192][256] (else null)
{
  const int b = blockIdx.x;
  const int t0 = threadIdx.x;
  const int j = t0 >> 1;        // h index 0..255
  const int half = t0 & 1;      // K-half: elements [half*128, half*128+128)
  __shared__ __align__(16) uint32_t hpk[2][128];

  // even lane uses (rowA=r-row j, rowB=z-row 256+j); odd lane (rowA=n-row 512+j)
  const int rowA = half ? 512 + j : j;
  const int rowB = half ? 512 + j : 256 + j;

  float xb0 = bih[rowA], xb1 = bih[rowB];
  const float bh0 = bhh[rowA], bh1 = bhh[rowB];

  if (Wih2) {  // xg2_base += Wih2[:, :256] @ h1 (prologue, before w preload)
    const float4* hb = (const float4*)(h1in + b * 256);
    const float4* wa = (const float4*)(Wih2 + (size_t)rowA * 1280);
    const float4* wb = (const float4*)(Wih2 + (size_t)rowB * 1280);
    float sa = 0.f, sb = 0.f;
#pragma unroll 2
    for (int k = 0; k < 64; ++k) {
      float4 h4 = hb[k], a4 = wa[k], b4 = wb[k];
      sa += a4.x * h4.x + a4.y * h4.y + a4.z * h4.z + a4.w * h4.w;
      sb += b4.x * h4.x + b4.y * h4.y + b4.z * h4.z + b4.w * h4.w;
    }
    xb0 += sa; xb1 += sb;
  }

  // preload half-K weight slices of rows r,z,n : 48 uint4 = 192 VGPRs
  uint4 wr[16], wz[16], wn[16];
  {
    const uint4* wp = (const uint4*)Wpk;
    const uint4* pr_ = wp + (size_t)j * 32 + half * 16;
    const uint4* pz_ = wp + (size_t)(256 + j) * 32 + half * 16;
    const uint4* pn_ = wp + (size_t)(512 + j) * 32 + half * 16;
#pragma unroll
    for (int i = 0; i < 16; ++i) { wr[i] = pr_[i]; wz[i] = pz_[i]; wn[i] = pn_[i]; }
  }

  if (t0 < 128) hpk[0][t0] = 0u;
  float hprev = 0.f;              // odd lanes: own h[j]
  __syncthreads();

  const float* xp0 = xg_all + (size_t)b * 1536 + xg_off + rowA;
  const float* xp1 = xg_all + (size_t)b * 1536 + xg_off + rowB;
  float xc0 = xp0[0], xc1 = xp1[0];
  ushort* pout = preds ? (preds + (size_t)b * 256 + j) : nullptr;

  for (int t = 0; t < 128; ++t) {
    const int tn = (t + 1 < 128) ? t + 1 : 127;
    float xn0 = xp0[(size_t)tn * 98304];   // prefetch next step (64*1536)
    float xn1 = xp1[(size_t)tn * 98304];

    float pr0 = 0.f, pr1 = 0.f, pz0 = 0.f, pz1 = 0.f, pn0 = 0.f, pn1 = 0.f;
    const uint4* hb = (const uint4*)(hpk[t & 1]) + half * 16;
#pragma unroll
    for (int i = 0; i < 16; ++i) {
      uint4 hv = hb[i];                    // 2-way broadcast across wave (free)
      pr0 = FDOT2(h2cast(wr[i].x), h2cast(hv.x), pr0);
      pz0 = FDOT2(h2cast(wz[i].x), h2cast(hv.x), pz0);
      pn0 = FDOT2(h2cast(wn[i].x), h2cast(hv.x), pn0);
      pr1 = FDOT2(h2cast(wr[i].y), h2cast(hv.y), pr1);
      pz1 = FDOT2(h2cast(wz[i].y), h2cast(hv.y), pz1);
      pn1 = FDOT2(h2cast(wn[i].y), h2cast(hv.y), pn1);
      pr0 = FDOT2(h2cast(wr[i].z), h2cast(hv.z), pr0);
      pz0 = FDOT2(h2cast(wz[i].z), h2cast(hv.z), pz0);
      pn0 = FDOT2(h2cast(wn[i].z), h2cast(hv.z), pn0);
      pr1 = FDOT2(h2cast(wr[i].w), h2cast(hv.w), pr1);
      pz1 = FDOT2(h2cast(wz[i].w), h2cast(hv.w), pz1);
      pn1 = FDOT2(h2cast(wn[i].w), h2cast(hv.w), pn1);
    }
    float hr = pr0 + pr1, hz = pz0 + pz1, hn = pn0 + pn1;
    hr += __shfl_xor(hr, 1);               // butterfly: both lanes get full dot
    hz += __shfl_xor(hz, 1);
    hn += __shfl_xor(hn, 1);

    // even lane: r and z (odd computes garbage, discarded via shfl direction)
    float s0 = 1.f / (1.f + __expf(-(xc0 + xb0 + hr + bh0)));
    float s1 = 1.f / (1.f + __expf(-(xc1 + xb1 + hz + bh1)));
    float rv = __shfl_xor(s0, 1);          // odd lane receives even's r
    float zv = __shfl_xor(s1, 1);          // odd lane receives even's z

    // odd lane: n-gate + h update (even-lane results unused)
    float x2 = xc0 + xb0 + rv * (hn + bh0);
    x2 = fminf(fmaxf(x2, -15.f), 15.f);
    float e = __expf(-2.f * x2);
    float nn = (1.f - e) / (1.f + e);
    float hnew = (1.f - zv) * nn + zv * hprev;
    float hup = __shfl_xor(hnew, 2);       // lane 4k+1 <- lane 4k+3 (h[2k+1])
    if (half) {
      hprev = hnew;
      if (pout) pout[(size_t)t * 16384] = f2bf(hnew);
      if ((t0 & 2) == 0) {                 // lanes == 1 (mod 4) pack h pair
        half2v hh; hh.x = (_Float16)hnew; hh.y = (_Float16)hup;
        hpk[(t + 1) & 1][t0 >> 2] = __builtin_bit_cast(uint32_t, hh);
      }
    }
    xc0 = xn0; xc1 = xn1;
    __syncthreads();                       // single barrier per step
  }

  if (half) {
    if (hfin_ws)  hfin_ws[b * 256 + j] = hprev;
    if (hfin_out) hfin_out[b * 256 + j] = hprev;
  }
}

// ---------------------------------------------------------------------------
extern "C" void kernel_launch(void* const* d_in, const int* in_sizes, int n_in,
                              void* d_out, int out_size, void* d_ws, size_t ws_size,
                              hipStream_t stream) {
  const int*   tokens = (const int*)d_in[0];
  const float* E      = (const float*)d_in[1];
  const float* Wih1   = (const float*)d_in[2];
  const float* Whh1   = (const float*)d_in[3];
  const float* bih1   = (const float*)d_in[4];
  const float* bhh1   = (const float*)d_in[5];
  const float* Wih2   = (const float*)d_in[6];
  const float* Whh2   = (const float*)d_in[7];
  const float* bih2   = (const float*)d_in[8];
  const float* bhh2   = (const float*)d_in[9];
  // d_in[10..14]: Wh, bh, Wi, bi, w_att — provably unused (softmax sums to 1,
  // h1 is t-invariant => state == h1 exactly).
  const float* Wd     = (const float*)d_in[15];
  const float* bd     = (const float*)d_in[16];
  float* out = (float*)d_out;

  char* ws = (char*)d_ws;
  ushort*   emb   = (ushort*)  (ws + 0);          // 16,777,216 B
  ushort*   w1cat = (ushort*)  (ws + 16777216);   //  3,145,728 B
  float*    xg    = (float*)   (ws + 19922944);   // 50,331,648 B
  ushort*   wdb   = (ushort*)  (ws + 70254592);   //  5,177,344 B
  uint32_t* whh1p = (uint32_t*)(ws + 75431936);   //    393,216 B
  uint32_t* whh2p = (uint32_t*)(ws + 75825152);   //    393,216 B (contig w/ whh1p)
  float*    h1    = (float*)   (ws + 76218368);   //     65,536 B
  ushort*   preds = (ushort*)  (ws + 76283904);   //  4,194,304 B

  cvt_w1cat<<<1536, 256, 0, stream>>>(Wih1, Wih2, w1cat);
  cvt_wd<<<2528, 256, 0, stream>>>(Wd, wdb);
  cvt_whh<<<768, 256, 0, stream>>>(Whh1, Whh2, whh1p);  // fills whh1p+whh2p
  gather_emb<<<8192, 256, 0, stream>>>(tokens, E, emb);

  dim3 g1(64, 12);   // [8192 x 1536 x 1024]
  gemm_bt<false, false><<<g1, 256, 0, stream>>>(emb, w1cat, xg, nullptr, 8192, 1024, 1536);

  gru_scan<<<64, 512, 0, stream>>>(whh1p, xg, 0, bih1, bhh1,
                                   nullptr, nullptr, h1, out + 81920000, nullptr);
  gru_scan<<<64, 512, 0, stream>>>(whh2p, xg, 768, bih2, bhh2,
                                   Wih2, h1, nullptr, nullptr, preds);

  dim3 g2(64, 79);   // [8192 x 10112(pad of 10000) x 256]
  gemm_bt<true, true><<<g2, 256, 0, stream>>>(preds, wdb, out, bd, 8192, 256, 10000);
}

// Round 2
// 862.383 us; speedup vs baseline: 1.0233x; 1.0116x over previous
//
#include <hip/hip_runtime.h>
#include <cstdint>
#include <cstddef>

#define DI __device__ __forceinline__

typedef short bf16x8 __attribute__((ext_vector_type(8)));
typedef float f32x4  __attribute__((ext_vector_type(4)));
typedef _Float16 half2v __attribute__((ext_vector_type(2)));

typedef const uint32_t __attribute__((address_space(1)))* gptr_t;
typedef uint32_t       __attribute__((address_space(3)))* lptr_t;

DI void load_lds16(const void* g, void* l_wave_uniform) {
#if __has_builtin(__builtin_amdgcn_global_load_lds)
  __builtin_amdgcn_global_load_lds((gptr_t)g, (lptr_t)l_wave_uniform, 16, 0, 0);
#else
  int lane = threadIdx.x & 63;
  *(uint4*)((char*)l_wave_uniform + lane * 16) = *(const uint4*)g;
#endif
}

DI ushort f2bf(float f) {  // round-to-nearest-even fp32 -> bf16
  uint32_t u = __builtin_bit_cast(uint32_t, f);
  u += 0x7fffu + ((u >> 16) & 1u);
  return (ushort)(u >> 16);
}

DI half2v h2cast(uint32_t u) { return __builtin_bit_cast(half2v, u); }

#if __has_builtin(__builtin_amdgcn_fdot2)
#define FDOT2(a, b, c) __builtin_amdgcn_fdot2((a), (b), (c), false)
#else
DI float fdot2_fb(half2v a, half2v b, float c) {
  return c + (float)a.x * (float)b.x + (float)a.y * (float)b.y;
}
#define FDOT2(a, b, c) fdot2_fb((a), (b), (c))
#endif

// ---------------------------------------------------------------------------
// Weight conversion kernels
// ---------------------------------------------------------------------------

// W1cat[1536][1024] bf16: rows 0..767 = Wih1, rows 768..1535 = Wih2[:,256:1280]
__global__ void cvt_w1cat(const float* __restrict__ W1, const float* __restrict__ W2,
                          ushort* __restrict__ dst) {
  int idx = blockIdx.x * 256 + threadIdx.x;   // 0 .. 393215
  int e = idx * 4;
  int row = e >> 10;
  int col = e & 1023;
  const float* src = (row < 768) ? (W1 + (size_t)row * 1024 + col)
                                 : (W2 + (size_t)(row - 768) * 1280 + 256 + col);
  float4 f = *(const float4*)src;
  ushort4 o; o.x = f2bf(f.x); o.y = f2bf(f.y); o.z = f2bf(f.z); o.w = f2bf(f.w);
  *(ushort4*)(dst + e) = o;
}

// Wd_bf16 padded [10112][256]
__global__ void cvt_wd(const float* __restrict__ Wd, ushort* __restrict__ dst) {
  int idx = blockIdx.x * 256 + threadIdx.x;   // 0 .. 647167
  int e = idx * 4;
  int row = e >> 8;
  int col = e & 255;
  ushort4 o;
  if (row < 10000) {
    float4 f = *(const float4*)(Wd + (size_t)row * 256 + col);
    o.x = f2bf(f.x); o.y = f2bf(f.y); o.z = f2bf(f.z); o.w = f2bf(f.w);
  } else {
    o.x = 0; o.y = 0; o.z = 0; o.w = 0;
  }
  *(ushort4*)(dst + e) = o;
}

// Whh1[768][256] + Whh2[768][256] fp32 -> packed f16 pairs, contiguous
// dst[0..98303] = Whh1 packed, dst[98304..196607] = Whh2 packed (one launch)
__global__ void cvt_whh(const float* __restrict__ W1, const float* __restrict__ W2,
                        uint32_t* __restrict__ dst) {
  int idx = blockIdx.x * 256 + threadIdx.x;   // 0 .. 196607
  const float* W = W1;
  int i = idx;
  if (i >= 98304) { W = W2; i -= 98304; }
  int row = i >> 7;
  int p = i & 127;
  float2 f = *(const float2*)(W + (size_t)row * 256 + p * 2);
  half2v h; h.x = (_Float16)f.x; h.y = (_Float16)f.y;
  dst[idx] = __builtin_bit_cast(uint32_t, h);
}

// emb gather: row r = t*B+b, E[token[r]] fp32 -> bf16 [8192][1024]
__global__ void gather_emb(const int* __restrict__ tok, const float* __restrict__ E,
                           ushort* __restrict__ emb) {
  int row = blockIdx.x;
  int t = threadIdx.x;          // 0..255, 4 elems each
  int v = tok[row];
  float4 f = *((const float4*)(E + (size_t)v * 1024) + t);
  ushort4 o; o.x = f2bf(f.x); o.y = f2bf(f.y); o.z = f2bf(f.z); o.w = f2bf(f.w);
  *((ushort4*)(emb + (size_t)row * 1024) + t) = o;
}

// ---------------------------------------------------------------------------
// GEMM: C[M,Nout] = A[M,K] * B[Npad,K]^T (+bias).  A,B bf16 K-contig, C fp32.
// BM=BN=128, BK=64, 256 threads (4 waves), each wave a 64x64 subtile.
// LDS chunk-XOR swizzle: 16B chunk c of row r lives at physical chunk c^(r&7).
// T1: XCD-chunked block swizzle (requires gridDim.x*gridDim.y % 8 == 0) so
// consecutive M-tiles sharing a B-panel land on ONE XCD's L2 instead of
// round-robining across 8 L2s (8x redundant B-panel fetch).
// NT: non-temporal C stores (logits written once, never re-read) keep the
// 327 MB dead stream from evicting A/B panels out of L2.
// ---------------------------------------------------------------------------
template <bool BIAS, bool GUARD, bool NT>
__global__ __launch_bounds__(256) void gemm_bt(
    const ushort* __restrict__ A, const ushort* __restrict__ B,
    float* __restrict__ C, const float* __restrict__ bias, int M, int K, int Nout) {
  __shared__ __align__(16) ushort As[128 * 64];
  __shared__ __align__(16) ushort Bs[128 * 64];
  const int t = threadIdx.x;
  const int wave = t >> 6, lane = t & 63;

  // T1 swizzle: linear bid -> (xcd chunk, contiguous run of M-tiles)
  const int nbx = gridDim.x;
  const int nwg = nbx * gridDim.y;
  const int bid = blockIdx.y * nbx + blockIdx.x;
  const int cpx = nwg >> 3;                    // blocks per XCD (nwg % 8 == 0)
  const int nbid = (bid & 7) * cpx + (bid >> 3);
  const int m0 = (nbid % nbx) * 128, n0 = (nbid / nbx) * 128;

  const int RM = (wave >> 1) * 64, RN = (wave & 1) * 64;
  const int lm = lane & 15, kg = lane >> 4;   // kg in 0..3

  f32x4 acc[4][4] = {};

  for (int k0 = 0; k0 < K; k0 += 64) {
#pragma unroll
    for (int i = 0; i < 4; ++i) {
      int off = i * 4096 + t * 16;       // byte offset within 16KB tile
      int row = off >> 7;                // /128 bytes per row
      int physc = (off >> 4) & 7;        // physical 16B chunk within row
      int gc = physc ^ (row & 7);        // logical (global) chunk
      int ub = i * 4096 + wave * 1024;   // wave-uniform LDS byte base
      const ushort* ga = A + (size_t)(m0 + row) * K + k0 + gc * 8;
      load_lds16(ga, (char*)As + ub);
      const ushort* gb = B + (size_t)(n0 + row) * K + k0 + gc * 8;
      load_lds16(gb, (char*)Bs + ub);
    }
    __syncthreads();
#pragma unroll
    for (int kk = 0; kk < 64; kk += 32) {
      const int lc = (kk >> 3) + kg;     // logical chunk for this fragment
      bf16x8 af[4], bfr[4];
#pragma unroll
      for (int i = 0; i < 4; ++i) {
        int ra = RM + i * 16 + lm;
        int rb = RN + i * 16 + lm;
        af[i]  = *(const bf16x8*)(As + ra * 64 + ((lc ^ (ra & 7)) << 3));
        bfr[i] = *(const bf16x8*)(Bs + rb * 64 + ((lc ^ (rb & 7)) << 3));
      }
#pragma unroll
      for (int i = 0; i < 4; ++i)
#pragma unroll
        for (int j = 0; j < 4; ++j)
          acc[i][j] = __builtin_amdgcn_mfma_f32_16x16x32_bf16(af[i], bfr[j], acc[i][j], 0, 0, 0);
    }
    __syncthreads();
  }

  const int rg = lane >> 4;   // row group 0..3
#pragma unroll
  for (int i = 0; i < 4; ++i) {
    int grow = m0 + RM + i * 16 + rg * 4;
#pragma unroll
    for (int j = 0; j < 4; ++j) {
      int gcol = n0 + RN + j * 16 + lm;
      if (GUARD && gcol >= Nout) continue;
      float bv = BIAS ? bias[gcol] : 0.f;
#pragma unroll
      for (int r = 0; r < 4; ++r) {
        float v = acc[i][j][r] + bv;
        float* p = C + (size_t)(grow + r) * Nout + gcol;
        if (NT) __builtin_nontemporal_store(v, p);
        else    *p = v;
      }
    }
  }
}

// ---------------------------------------------------------------------------
// GRU scan v2: one 512-thread block per batch element.
// Lane pair (t, t^1) splits K=256 in half; EACH thread computes the partial
// dot of ALL THREE gate rows (r=j, z=256+j, n=512+j) for its h-index j=t>>1
// over its K-half.  Recurrent weights register-resident: 3 x 16 uint4 = 192
// VGPRs.  VALU-throughput-bound at ~768 cy/step/CU (FDOT2 floor) — near its
// structural floor; scan work cannot spread past 64 CUs (64 batch elements,
// sequential t).
// ---------------------------------------------------------------------------
__global__ __launch_bounds__(512, 2) void gru_scan(
    const uint32_t* __restrict__ Wpk,      // [768][128] f16-pairs of Whh
    const float* __restrict__ xg_all,      // [8192][1536] fp32 input gates
    int xg_off,
    const float* __restrict__ bih, const float* __restrict__ bhh,
    const float* __restrict__ Wih2,        // gru2 only: [768][1280] fp32 (else null)
    const float* __restrict__ h1in,        // gru2 only: [64][256] fp32
    float* __restrict__ hfin_ws,           // gru1: h1 scratch (else null)
    float* __restrict__ hfin_out,          // gru1: d_out h1 region (else null)
    ushort* __restrict__ preds)            // gru2: bf16 [8192][256] (else null)
{
  const int b = blockIdx.x;
  const int t0 = threadIdx.x;
  const int j = t0 >> 1;        // h index 0..255
  const int half = t0 & 1;      // K-half: elements [half*128, half*128+128)
  __shared__ __align__(16) uint32_t hpk[2][128];

  // even lane uses (rowA=r-row j, rowB=z-row 256+j); odd lane (rowA=n-row 512+j)
  const int rowA = half ? 512 + j : j;
  const int rowB = half ? 512 + j : 256 + j;

  float xb0 = bih[rowA], xb1 = bih[rowB];
  const float bh0 = bhh[rowA], bh1 = bhh[rowB];

  if (Wih2) {  // xg2_base += Wih2[:, :256] @ h1 (prologue, before w preload)
    const float4* hb = (const float4*)(h1in + b * 256);
    const float4* wa = (const float4*)(Wih2 + (size_t)rowA * 1280);
    const float4* wb = (const float4*)(Wih2 + (size_t)rowB * 1280);
    float sa = 0.f, sb = 0.f;
#pragma unroll 2
    for (int k = 0; k < 64; ++k) {
      float4 h4 = hb[k], a4 = wa[k], b4 = wb[k];
      sa += a4.x * h4.x + a4.y * h4.y + a4.z * h4.z + a4.w * h4.w;
      sb += b4.x * h4.x + b4.y * h4.y + b4.z * h4.z + b4.w * h4.w;
    }
    xb0 += sa; xb1 += sb;
  }

  // preload half-K weight slices of rows r,z,n : 48 uint4 = 192 VGPRs
  uint4 wr[16], wz[16], wn[16];
  {
    const uint4* wp = (const uint4*)Wpk;
    const uint4* pr_ = wp + (size_t)j * 32 + half * 16;
    const uint4* pz_ = wp + (size_t)(256 + j) * 32 + half * 16;
    const uint4* pn_ = wp + (size_t)(512 + j) * 32 + half * 16;
#pragma unroll
    for (int i = 0; i < 16; ++i) { wr[i] = pr_[i]; wz[i] = pz_[i]; wn[i] = pn_[i]; }
  }

  if (t0 < 128) hpk[0][t0] = 0u;
  float hprev = 0.f;              // odd lanes: own h[j]
  __syncthreads();

  const float* xp0 = xg_all + (size_t)b * 1536 + xg_off + rowA;
  const float* xp1 = xg_all + (size_t)b * 1536 + xg_off + rowB;
  float xc0 = xp0[0], xc1 = xp1[0];
  ushort* pout = preds ? (preds + (size_t)b * 256 + j) : nullptr;

  for (int t = 0; t < 128; ++t) {
    const int tn = (t + 1 < 128) ? t + 1 : 127;
    float xn0 = xp0[(size_t)tn * 98304];   // prefetch next step (64*1536)
    float xn1 = xp1[(size_t)tn * 98304];

    float pr0 = 0.f, pr1 = 0.f, pz0 = 0.f, pz1 = 0.f, pn0 = 0.f, pn1 = 0.f;
    const uint4* hb = (const uint4*)(hpk[t & 1]) + half * 16;
#pragma unroll
    for (int i = 0; i < 16; ++i) {
      uint4 hv = hb[i];                    // 2-way broadcast across wave (free)
      pr0 = FDOT2(h2cast(wr[i].x), h2cast(hv.x), pr0);
      pz0 = FDOT2(h2cast(wz[i].x), h2cast(hv.x), pz0);
      pn0 = FDOT2(h2cast(wn[i].x), h2cast(hv.x), pn0);
      pr1 = FDOT2(h2cast(wr[i].y), h2cast(hv.y), pr1);
      pz1 = FDOT2(h2cast(wz[i].y), h2cast(hv.y), pz1);
      pn1 = FDOT2(h2cast(wn[i].y), h2cast(hv.y), pn1);
      pr0 = FDOT2(h2cast(wr[i].z), h2cast(hv.z), pr0);
      pz0 = FDOT2(h2cast(wz[i].z), h2cast(hv.z), pz0);
      pn0 = FDOT2(h2cast(wn[i].z), h2cast(hv.z), pn0);
      pr1 = FDOT2(h2cast(wr[i].w), h2cast(hv.w), pr1);
      pz1 = FDOT2(h2cast(wz[i].w), h2cast(hv.w), pz1);
      pn1 = FDOT2(h2cast(wn[i].w), h2cast(hv.w), pn1);
    }
    float hr = pr0 + pr1, hz = pz0 + pz1, hn = pn0 + pn1;
    hr += __shfl_xor(hr, 1);               // butterfly: both lanes get full dot
    hz += __shfl_xor(hz, 1);
    hn += __shfl_xor(hn, 1);

    // even lane: r and z (odd computes garbage, discarded via shfl direction)
    float s0 = 1.f / (1.f + __expf(-(xc0 + xb0 + hr + bh0)));
    float s1 = 1.f / (1.f + __expf(-(xc1 + xb1 + hz + bh1)));
    float rv = __shfl_xor(s0, 1);          // odd lane receives even's r
    float zv = __shfl_xor(s1, 1);          // odd lane receives even's z

    // odd lane: n-gate + h update (even-lane results unused)
    float x2 = xc0 + xb0 + rv * (hn + bh0);
    x2 = fminf(fmaxf(x2, -15.f), 15.f);
    float e = __expf(-2.f * x2);
    float nn = (1.f - e) / (1.f + e);
    float hnew = (1.f - zv) * nn + zv * hprev;
    float hup = __shfl_xor(hnew, 2);       // lane 4k+1 <- lane 4k+3 (h[2k+1])
    if (half) {
      hprev = hnew;
      if (pout) pout[(size_t)t * 16384] = f2bf(hnew);
      if ((t0 & 2) == 0) {                 // lanes == 1 (mod 4) pack h pair
        half2v hh; hh.x = (_Float16)hnew; hh.y = (_Float16)hup;
        hpk[(t + 1) & 1][t0 >> 2] = __builtin_bit_cast(uint32_t, hh);
      }
    }
    xc0 = xn0; xc1 = xn1;
    __syncthreads();                       // single barrier per step
  }

  if (half) {
    if (hfin_ws)  hfin_ws[b * 256 + j] = hprev;
    if (hfin_out) hfin_out[b * 256 + j] = hprev;
  }
}

// ---------------------------------------------------------------------------
extern "C" void kernel_launch(void* const* d_in, const int* in_sizes, int n_in,
                              void* d_out, int out_size, void* d_ws, size_t ws_size,
                              hipStream_t stream) {
  const int*   tokens = (const int*)d_in[0];
  const float* E      = (const float*)d_in[1];
  const float* Wih1   = (const float*)d_in[2];
  const float* Whh1   = (const float*)d_in[3];
  const float* bih1   = (const float*)d_in[4];
  const float* bhh1   = (const float*)d_in[5];
  const float* Wih2   = (const float*)d_in[6];
  const float* Whh2   = (const float*)d_in[7];
  const float* bih2   = (const float*)d_in[8];
  const float* bhh2   = (const float*)d_in[9];
  // d_in[10..14]: Wh, bh, Wi, bi, w_att — provably unused (softmax sums to 1,
  // h1 is t-invariant => state == h1 exactly).
  const float* Wd     = (const float*)d_in[15];
  const float* bd     = (const float*)d_in[16];
  float* out = (float*)d_out;

  char* ws = (char*)d_ws;
  ushort*   emb   = (ushort*)  (ws + 0);          // 16,777,216 B
  ushort*   w1cat = (ushort*)  (ws + 16777216);   //  3,145,728 B
  float*    xg    = (float*)   (ws + 19922944);   // 50,331,648 B
  ushort*   wdb   = (ushort*)  (ws + 70254592);   //  5,177,344 B
  uint32_t* whh1p = (uint32_t*)(ws + 75431936);   //    393,216 B
  uint32_t* whh2p = (uint32_t*)(ws + 75825152);   //    393,216 B (contig w/ whh1p)
  float*    h1    = (float*)   (ws + 76218368);   //     65,536 B
  ushort*   preds = (ushort*)  (ws + 76283904);   //  4,194,304 B

  cvt_w1cat<<<1536, 256, 0, stream>>>(Wih1, Wih2, w1cat);
  cvt_wd<<<2528, 256, 0, stream>>>(Wd, wdb);
  cvt_whh<<<768, 256, 0, stream>>>(Whh1, Whh2, whh1p);  // fills whh1p+whh2p
  gather_emb<<<8192, 256, 0, stream>>>(tokens, E, emb);

  dim3 g1(64, 12);   // [8192 x 1536 x 1024], nwg=768 (%8==0 for T1 swizzle)
  gemm_bt<false, false, false><<<g1, 256, 0, stream>>>(emb, w1cat, xg, nullptr, 8192, 1024, 1536);

  gru_scan<<<64, 512, 0, stream>>>(whh1p, xg, 0, bih1, bhh1,
                                   nullptr, nullptr, h1, out + 81920000, nullptr);
  gru_scan<<<64, 512, 0, stream>>>(whh2p, xg, 768, bih2, bhh2,
                                   Wih2, h1, nullptr, nullptr, preds);

  dim3 g2(64, 79);   // [8192 x 10112(pad of 10000) x 256], nwg=5056 (%8==0)
  gemm_bt<true, true, true><<<g2, 256, 0, stream>>>(preds, wdb, out, bd, 8192, 256, 10000);
}